// Round 1
// baseline (1099.227 us; speedup 1.0000x reference)
//
#include <hip/hip_runtime.h>
#include <math.h>

// ---------------------------------------------------------------------------
// AGNNet: GAT-like 3-layer GNN. N=100000 nodes, E=800000 edges, HID=64.
// Strategy: per-node attention projections (ai/aj) instead of per-edge dots;
// wave-per-node GEMMs with W in LDS; atomicAdd-based segment sums (baseline).
// ---------------------------------------------------------------------------

#define HID 64
#define INC 128

// Kernel A: h0 = relu(x @ W_in + b_in); delta=sum|h0|; hwp=h0.wp; ai=h0.w_i; aj=h0.w_j
__global__ __launch_bounds__(256) void k_in_gemm(
    const float* __restrict__ x, const float* __restrict__ Win,
    const float* __restrict__ bin, const float* __restrict__ wp,
    const float* __restrict__ attw,
    float* __restrict__ h0, float* __restrict__ delta, float* __restrict__ hwp,
    float* __restrict__ ai, float* __restrict__ aj, int n)
{
    __shared__ float Wl[INC * HID];   // 32 KB
    for (int i = threadIdx.x; i < INC * HID; i += 256) Wl[i] = Win[i];
    __syncthreads();

    const int wave = threadIdx.x >> 6;
    const int lane = threadIdx.x & 63;
    const float bc  = bin[lane];
    const float wpc = wp[lane];
    const float wic = attw[lane];
    const float wjc = attw[HID + lane];

    for (int node = blockIdx.x * 4 + wave; node < n; node += gridDim.x * 4) {
        const float* xr = x + (size_t)node * INC;
        float acc = bc;
        #pragma unroll 8
        for (int k = 0; k < INC; ++k)
            acc = fmaf(xr[k], Wl[k * HID + lane], acc);
        float h = acc > 0.f ? acc : 0.f;
        h0[(size_t)node * HID + lane] = h;

        float vd = fabsf(h);
        float vw = h * wpc;
        float vi = h * wic;
        float vj = h * wjc;
        #pragma unroll
        for (int m = 32; m; m >>= 1) {
            vd += __shfl_xor(vd, m);
            vw += __shfl_xor(vw, m);
            vi += __shfl_xor(vi, m);
            vj += __shfl_xor(vj, m);
        }
        if (lane == 0) {
            delta[node] = vd; hwp[node] = vw; ai[node] = vi; aj[node] = vj;
        }
    }
}

// Kernel B: neigh_sum[dst] += delta[src]
__global__ __launch_bounds__(256) void k_neigh(
    const int* __restrict__ src, const int* __restrict__ dst,
    const float* __restrict__ delta, float* __restrict__ neigh, int E)
{
    int e = blockIdx.x * 256 + threadIdx.x;
    if (e < E) atomicAdd(neigh + dst[e], delta[src[e]]);
}

// Kernel C: pi = sigmoid(hwp + neigh)
__global__ __launch_bounds__(256) void k_pi(
    const float* __restrict__ hwp, const float* __restrict__ neigh,
    float* __restrict__ pi, int n)
{
    int i = blockIdx.x * 256 + threadIdx.x;
    if (i < n) {
        float v = hwp[i] + neigh[i];
        pi[i] = 1.f / (1.f + expf(-v));
    }
}

// Kernel D: e = lrelu(ai[dst]+aj[src]+pi[src]*w_p+att_b); expe=exp(e); denom[dst]+=expe
__global__ __launch_bounds__(256) void k_edge_e(
    const int* __restrict__ src, const int* __restrict__ dst,
    const float* __restrict__ ai, const float* __restrict__ aj,
    const float* __restrict__ pi, const float* __restrict__ attw,
    const float* __restrict__ attb,
    float* __restrict__ expe, float* __restrict__ denom, int E)
{
    int e = blockIdx.x * 256 + threadIdx.x;
    if (e < E) {
        int s = src[e], d = dst[e];
        float v = ai[d] + aj[s] + pi[s] * attw[2 * HID] + attb[0];
        v = v > 0.f ? v : 0.2f * v;
        float ev = expf(v);
        expe[e] = ev;
        atomicAdd(denom + d, ev);
    }
}

// Kernel E: alpha = expe / (denom[dst] + 1e-16)
__global__ __launch_bounds__(256) void k_alpha(
    const int* __restrict__ dst, const float* __restrict__ denom,
    float* __restrict__ expe_alpha, int E)
{
    int e = blockIdx.x * 256 + threadIdx.x;
    if (e < E)
        expe_alpha[e] = expe_alpha[e] / (denom[dst[e]] + 1e-16f);
}

// Kernel F: 64x64 GEMM per node (wave-per-node), optional relu on input
__global__ __launch_bounds__(256) void k_gemm64(
    const float* __restrict__ hin, const float* __restrict__ W,
    const float* __restrict__ b, float* __restrict__ hout, int n, int relu_in)
{
    __shared__ float Wl[HID * HID];   // 16 KB
    for (int i = threadIdx.x; i < HID * HID; i += 256) Wl[i] = W[i];
    __syncthreads();

    const int wave = threadIdx.x >> 6;
    const int lane = threadIdx.x & 63;
    const float bc = b[lane];

    for (int node = blockIdx.x * 4 + wave; node < n; node += gridDim.x * 4) {
        const float* hr = hin + (size_t)node * HID;
        float acc = bc;
        #pragma unroll 8
        for (int k = 0; k < HID; ++k) {
            float hv = hr[k];
            if (relu_in) hv = fmaxf(hv, 0.f);
            acc = fmaf(hv, Wl[k * HID + lane], acc);
        }
        hout[(size_t)node * HID + lane] = acc;
    }
}

// Kernel G: scatter msg: hn[dst*64+c] += alpha[e]*hl[src*64+c]  (wave per edge)
__global__ __launch_bounds__(256) void k_scatter(
    const int* __restrict__ src, const int* __restrict__ dst,
    const float* __restrict__ alpha, const float* __restrict__ hl,
    float* __restrict__ hn, int E)
{
    int gid = blockIdx.x * 256 + threadIdx.x;
    int e = gid >> 6;
    int c = gid & 63;
    if (e < E) {
        float a = alpha[e];
        float v = a * hl[(size_t)src[e] * HID + c];
        atomicAdd(hn + (size_t)dst[e] * HID + c, v);
    }
}

// Kernel H: out = relu(h) @ W_out + b_out   (64x40)
__global__ __launch_bounds__(256) void k_out_gemm(
    const float* __restrict__ hin, const float* __restrict__ W,
    const float* __restrict__ b, float* __restrict__ out, int n)
{
    __shared__ float Wl[HID * 40];    // 10 KB
    __shared__ float bl[40];
    for (int i = threadIdx.x; i < HID * 40; i += 256) Wl[i] = W[i];
    if (threadIdx.x < 40) bl[threadIdx.x] = b[threadIdx.x];
    __syncthreads();

    const int wave = threadIdx.x >> 6;
    const int lane = threadIdx.x & 63;

    for (int node = blockIdx.x * 4 + wave; node < n; node += gridDim.x * 4) {
        const float* hr = hin + (size_t)node * HID;
        if (lane < 40) {
            float acc = bl[lane];
            #pragma unroll 8
            for (int k = 0; k < HID; ++k)
                acc = fmaf(fmaxf(hr[k], 0.f), Wl[k * 40 + lane], acc);
            out[(size_t)node * 40 + lane] = acc;
        }
    }
}

extern "C" void kernel_launch(void* const* d_in, const int* in_sizes, int n_in,
                              void* d_out, int out_size, void* d_ws, size_t ws_size,
                              hipStream_t stream) {
    const float* x    = (const float*)d_in[0];
    const int*   ei   = (const int*)d_in[1];
    const float* Win  = (const float*)d_in[2];
    const float* bin  = (const float*)d_in[3];
    const float* wp   = (const float*)d_in[4];
    const float* attw = (const float*)d_in[5];
    const float* attb = (const float*)d_in[6];
    const float* Wout = (const float*)d_in[7];
    const float* bout = (const float*)d_in[8];
    const float* W0   = (const float*)d_in[9];
    const float* b0   = (const float*)d_in[10];
    const float* W1   = (const float*)d_in[11];
    const float* b1   = (const float*)d_in[12];
    const float* W2   = (const float*)d_in[13];
    const float* b2   = (const float*)d_in[14];

    const int N = in_sizes[0] / INC;
    const int E = in_sizes[1] / 2;
    const int* src = ei;
    const int* dst = ei + E;
    float* out = (float*)d_out;

    char* ws = (char*)d_ws;
    size_t off = 0;
    auto alloc = [&](size_t bytes) -> void* {
        void* p = ws + off;
        off = (off + bytes + 255) & ~(size_t)255;
        return p;
    };
    float* A     = (float*)alloc((size_t)N * HID * 4);
    float* Bf    = (float*)alloc((size_t)N * HID * 4);
    float* C     = (float*)alloc((size_t)N * HID * 4);
    float* delta = (float*)alloc((size_t)N * 4);
    float* hwp   = (float*)alloc((size_t)N * 4);
    float* ai    = (float*)alloc((size_t)N * 4);
    float* aj    = (float*)alloc((size_t)N * 4);
    float* pi    = (float*)alloc((size_t)N * 4);
    float* neigh = (float*)alloc((size_t)N * 4);
    float* denom = (float*)alloc((size_t)N * 4);
    float* alpha = (float*)alloc((size_t)E * 4);

    const int nodeBlocks = (N + 3) / 4;          // wave-per-node kernels
    const int edgeBlocks = (E + 255) / 256;
    const int scatBlocks = (int)(((size_t)E * HID + 255) / 256);

    hipMemsetAsync(neigh, 0, (size_t)N * 4, stream);
    hipMemsetAsync(denom, 0, (size_t)N * 4, stream);

    // h0 + per-node reductions
    k_in_gemm<<<nodeBlocks, 256, 0, stream>>>(x, Win, bin, wp, attw,
                                              A, delta, hwp, ai, aj, N);
    // neigh_sum, pi
    k_neigh<<<edgeBlocks, 256, 0, stream>>>(src, dst, delta, neigh, E);
    k_pi<<<(N + 255) / 256, 256, 0, stream>>>(hwp, neigh, pi, N);
    // attention
    k_edge_e<<<edgeBlocks, 256, 0, stream>>>(src, dst, ai, aj, pi, attw, attb,
                                             alpha, denom, E);
    k_alpha<<<edgeBlocks, 256, 0, stream>>>(dst, denom, alpha, E);

    // Layer 0: hl = h0(A) @ W0 + b0 -> Bf ; scatter Bf -> C
    hipMemsetAsync(C, 0, (size_t)N * HID * 4, stream);
    k_gemm64<<<nodeBlocks, 256, 0, stream>>>(A, W0, b0, Bf, N, 0);
    k_scatter<<<scatBlocks, 256, 0, stream>>>(src, dst, alpha, Bf, C, E);

    // Layer 1: hl = relu(C) @ W1 + b1 -> A ; scatter A -> Bf
    k_gemm64<<<nodeBlocks, 256, 0, stream>>>(C, W1, b1, A, N, 1);
    hipMemsetAsync(Bf, 0, (size_t)N * HID * 4, stream);
    k_scatter<<<scatBlocks, 256, 0, stream>>>(src, dst, alpha, A, Bf, E);

    // Layer 2: hl = relu(Bf) @ W2 + b2 -> C ; scatter C -> A
    k_gemm64<<<nodeBlocks, 256, 0, stream>>>(Bf, W2, b2, C, N, 1);
    hipMemsetAsync(A, 0, (size_t)N * HID * 4, stream);
    k_scatter<<<scatBlocks, 256, 0, stream>>>(src, dst, alpha, C, A, E);

    // Output: out = relu(A) @ W_out + b_out
    k_out_gemm<<<nodeBlocks, 256, 0, stream>>>(A, Wout, bout, out, N);
}

// Round 2
// 760.177 us; speedup vs baseline: 1.4460x; 1.4460x over previous
//
#include <hip/hip_runtime.h>
#include <math.h>

// ---------------------------------------------------------------------------
// AGNNet: GAT-like 3-layer GNN. N=100000 nodes, E=800000 edges, HID=64.
// R2: LDS-tiled register-blocked GEMMs (4x4 per thread, float4 LDS reads,
// conflict-free padded tiles). Scatter/atomics unchanged (next target).
// ---------------------------------------------------------------------------

#define HID 64
#define INC 128

// Kernel A: h0 = relu(x @ W_in + b_in); fused per-node reductions:
// delta=sum|h0|, hwp=h0.wp, ai=h0.w_i, aj=h0.w_j
// Tile: 64 nodes x 64 cols. 256 thr: cx=t&15 (4 cols), ny=t>>4 (4 nodes i*16+ny).
__global__ __launch_bounds__(256) void k_in_gemm(
    const float* __restrict__ x, const float* __restrict__ Win,
    const float* __restrict__ bin, const float* __restrict__ wp,
    const float* __restrict__ attw,
    float* __restrict__ h0, float* __restrict__ delta, float* __restrict__ hwp,
    float* __restrict__ ai, float* __restrict__ aj, int n)
{
    __shared__ float xs[64 * 132];    // pad 132: node rows hit distinct banks
    __shared__ float Ws[INC * HID];   // 32 KB
    const int t = threadIdx.x;
    const int node0 = blockIdx.x * 64;

    #pragma unroll
    for (int p = 0; p < 8; ++p) {     // W: 8192 floats = 2048 float4
        int c = t + p * 256;
        *(float4*)&Ws[c * 4] = *(const float4*)&Win[c * 4];
    }
    #pragma unroll
    for (int p = 0; p < 8; ++p) {     // x: 64 rows x 128
        int c = t + p * 256;
        int row = c >> 5;
        int col = (c & 31) * 4;
        float4 v = make_float4(0.f, 0.f, 0.f, 0.f);
        if (node0 + row < n) v = *(const float4*)&x[(size_t)(node0 + row) * INC + col];
        *(float4*)&xs[row * 132 + col] = v;
    }
    __syncthreads();

    const int cx = t & 15;
    const int ny = t >> 4;
    float acc[4][4];
    const float4 bv = *(const float4*)&bin[cx * 4];
    #pragma unroll
    for (int i = 0; i < 4; ++i) {
        acc[i][0] = bv.x; acc[i][1] = bv.y; acc[i][2] = bv.z; acc[i][3] = bv.w;
    }

    #pragma unroll 4
    for (int k4 = 0; k4 < 32; ++k4) {
        float4 xv[4];
        #pragma unroll
        for (int i = 0; i < 4; ++i)
            xv[i] = *(const float4*)&xs[(i * 16 + ny) * 132 + k4 * 4];
        #pragma unroll
        for (int kk = 0; kk < 4; ++kk) {
            float4 w = *(const float4*)&Ws[(k4 * 4 + kk) * HID + cx * 4];
            #pragma unroll
            for (int i = 0; i < 4; ++i) {
                float xval = reinterpret_cast<const float*>(&xv[i])[kk];
                acc[i][0] = fmaf(xval, w.x, acc[i][0]);
                acc[i][1] = fmaf(xval, w.y, acc[i][1]);
                acc[i][2] = fmaf(xval, w.z, acc[i][2]);
                acc[i][3] = fmaf(xval, w.w, acc[i][3]);
            }
        }
    }

    const float4 wpv = *(const float4*)&wp[cx * 4];
    const float4 wiv = *(const float4*)&attw[cx * 4];
    const float4 wjv = *(const float4*)&attw[HID + cx * 4];

    #pragma unroll
    for (int i = 0; i < 4; ++i) {
        const int node = node0 + i * 16 + ny;
        float h0v = fmaxf(acc[i][0], 0.f);
        float h1v = fmaxf(acc[i][1], 0.f);
        float h2v = fmaxf(acc[i][2], 0.f);
        float h3v = fmaxf(acc[i][3], 0.f);
        if (node < n) {
            float4 hv = make_float4(h0v, h1v, h2v, h3v);
            *(float4*)&h0[(size_t)node * HID + cx * 4] = hv;
        }
        float vd = h0v + h1v + h2v + h3v;   // |relu(h)| == relu(h)
        float vw = h0v * wpv.x + h1v * wpv.y + h2v * wpv.z + h3v * wpv.w;
        float vi = h0v * wiv.x + h1v * wiv.y + h2v * wiv.z + h3v * wiv.w;
        float vj = h0v * wjv.x + h1v * wjv.y + h2v * wjv.z + h3v * wjv.w;
        #pragma unroll
        for (int m = 1; m < 16; m <<= 1) {
            vd += __shfl_xor(vd, m);
            vw += __shfl_xor(vw, m);
            vi += __shfl_xor(vi, m);
            vj += __shfl_xor(vj, m);
        }
        if (cx == 0 && node < n) {
            delta[node] = vd; hwp[node] = vw; ai[node] = vi; aj[node] = vj;
        }
    }
}

// Kernel B: neigh_sum[dst] += delta[src]
__global__ __launch_bounds__(256) void k_neigh(
    const int* __restrict__ src, const int* __restrict__ dst,
    const float* __restrict__ delta, float* __restrict__ neigh, int E)
{
    int e = blockIdx.x * 256 + threadIdx.x;
    if (e < E) atomicAdd(neigh + dst[e], delta[src[e]]);
}

// Kernel C: pi = sigmoid(hwp + neigh)
__global__ __launch_bounds__(256) void k_pi(
    const float* __restrict__ hwp, const float* __restrict__ neigh,
    float* __restrict__ pi, int n)
{
    int i = blockIdx.x * 256 + threadIdx.x;
    if (i < n) {
        float v = hwp[i] + neigh[i];
        pi[i] = 1.f / (1.f + expf(-v));
    }
}

// Kernel D: e = lrelu(ai[dst]+aj[src]+pi[src]*w_p+att_b); expe=exp(e); denom[dst]+=expe
__global__ __launch_bounds__(256) void k_edge_e(
    const int* __restrict__ src, const int* __restrict__ dst,
    const float* __restrict__ ai, const float* __restrict__ aj,
    const float* __restrict__ pi, const float* __restrict__ attw,
    const float* __restrict__ attb,
    float* __restrict__ expe, float* __restrict__ denom, int E)
{
    int e = blockIdx.x * 256 + threadIdx.x;
    if (e < E) {
        int s = src[e], d = dst[e];
        float v = ai[d] + aj[s] + pi[s] * attw[2 * HID] + attb[0];
        v = v > 0.f ? v : 0.2f * v;
        float ev = expf(v);
        expe[e] = ev;
        atomicAdd(denom + d, ev);
    }
}

// Kernel E: alpha = expe / (denom[dst] + 1e-16)
__global__ __launch_bounds__(256) void k_alpha(
    const int* __restrict__ dst, const float* __restrict__ denom,
    float* __restrict__ expe_alpha, int E)
{
    int e = blockIdx.x * 256 + threadIdx.x;
    if (e < E)
        expe_alpha[e] = expe_alpha[e] / (denom[dst[e]] + 1e-16f);
}

// Kernel F: 64x64 GEMM, tile 64 nodes x 64 cols, 4x4 per thread.
// relu_in applied at staging.
__global__ __launch_bounds__(256) void k_gemm64(
    const float* __restrict__ hin, const float* __restrict__ W,
    const float* __restrict__ b, float* __restrict__ hout, int n, int relu_in)
{
    __shared__ float xs[64 * 68];     // pad 68
    __shared__ float Ws[HID * HID];   // 16 KB
    const int t = threadIdx.x;
    const int node0 = blockIdx.x * 64;

    #pragma unroll
    for (int p = 0; p < 4; ++p) {     // W: 4096 floats = 1024 float4
        int c = t + p * 256;
        *(float4*)&Ws[c * 4] = *(const float4*)&W[c * 4];
    }
    #pragma unroll
    for (int p = 0; p < 4; ++p) {     // x: 64 rows x 64
        int c = t + p * 256;
        int row = c >> 4;
        int col = (c & 15) * 4;
        float4 v = make_float4(0.f, 0.f, 0.f, 0.f);
        if (node0 + row < n) v = *(const float4*)&hin[(size_t)(node0 + row) * HID + col];
        if (relu_in) {
            v.x = fmaxf(v.x, 0.f); v.y = fmaxf(v.y, 0.f);
            v.z = fmaxf(v.z, 0.f); v.w = fmaxf(v.w, 0.f);
        }
        *(float4*)&xs[row * 68 + col] = v;
    }
    __syncthreads();

    const int cx = t & 15;
    const int ny = t >> 4;
    float acc[4][4];
    const float4 bv = *(const float4*)&b[cx * 4];
    #pragma unroll
    for (int i = 0; i < 4; ++i) {
        acc[i][0] = bv.x; acc[i][1] = bv.y; acc[i][2] = bv.z; acc[i][3] = bv.w;
    }

    #pragma unroll 4
    for (int k4 = 0; k4 < 16; ++k4) {
        float4 xv[4];
        #pragma unroll
        for (int i = 0; i < 4; ++i)
            xv[i] = *(const float4*)&xs[(i * 16 + ny) * 68 + k4 * 4];
        #pragma unroll
        for (int kk = 0; kk < 4; ++kk) {
            float4 w = *(const float4*)&Ws[(k4 * 4 + kk) * HID + cx * 4];
            #pragma unroll
            for (int i = 0; i < 4; ++i) {
                float xval = reinterpret_cast<const float*>(&xv[i])[kk];
                acc[i][0] = fmaf(xval, w.x, acc[i][0]);
                acc[i][1] = fmaf(xval, w.y, acc[i][1]);
                acc[i][2] = fmaf(xval, w.z, acc[i][2]);
                acc[i][3] = fmaf(xval, w.w, acc[i][3]);
            }
        }
    }

    #pragma unroll
    for (int i = 0; i < 4; ++i) {
        const int node = node0 + i * 16 + ny;
        if (node < n) {
            float4 hv = make_float4(acc[i][0], acc[i][1], acc[i][2], acc[i][3]);
            *(float4*)&hout[(size_t)node * HID + cx * 4] = hv;
        }
    }
}

// Kernel G: scatter msg: hn[dst*64+c] += alpha[e]*hl[src*64+c]  (wave per edge)
__global__ __launch_bounds__(256) void k_scatter(
    const int* __restrict__ src, const int* __restrict__ dst,
    const float* __restrict__ alpha, const float* __restrict__ hl,
    float* __restrict__ hn, int E)
{
    int gid = blockIdx.x * 256 + threadIdx.x;
    int e = gid >> 6;
    int c = gid & 63;
    if (e < E) {
        float a = alpha[e];
        float v = a * hl[(size_t)src[e] * HID + c];
        atomicAdd(hn + (size_t)dst[e] * HID + c, v);
    }
}

// Kernel H: out = relu(h) @ W_out + b_out  (64x40)
// Tile 128 nodes x 40 cols; thread: cx=t&7 (5 cols), ny=t>>3 (4 nodes i*32+ny).
__global__ __launch_bounds__(256) void k_out_gemm(
    const float* __restrict__ hin, const float* __restrict__ W,
    const float* __restrict__ b, float* __restrict__ out, int n)
{
    __shared__ float xs[128 * 68];    // pad 68
    __shared__ float Ws[HID * 40];    // 10.2 KB
    const int t = threadIdx.x;
    const int node0 = blockIdx.x * 128;

    #pragma unroll
    for (int p = 0; p < 3; ++p) {     // W: 2560 floats = 640 float4
        int c = t + p * 256;
        if (c < 640) *(float4*)&Ws[c * 4] = *(const float4*)&W[c * 4];
    }
    #pragma unroll
    for (int p = 0; p < 8; ++p) {     // x: 128 rows x 64 (relu on stage)
        int c = t + p * 256;
        int row = c >> 4;
        int col = (c & 15) * 4;
        float4 v = make_float4(0.f, 0.f, 0.f, 0.f);
        if (node0 + row < n) v = *(const float4*)&hin[(size_t)(node0 + row) * HID + col];
        v.x = fmaxf(v.x, 0.f); v.y = fmaxf(v.y, 0.f);
        v.z = fmaxf(v.z, 0.f); v.w = fmaxf(v.w, 0.f);
        *(float4*)&xs[row * 68 + col] = v;
    }
    __syncthreads();

    const int cx = t & 7;             // 5 cols: 5*cx .. 5*cx+4
    const int ny = t >> 3;            // nodes i*32+ny
    float acc[4][5];
    #pragma unroll
    for (int j = 0; j < 5; ++j) {
        float bj = b[5 * cx + j];
        #pragma unroll
        for (int i = 0; i < 4; ++i) acc[i][j] = bj;
    }

    #pragma unroll 4
    for (int k4 = 0; k4 < 16; ++k4) {
        float4 xv[4];
        #pragma unroll
        for (int i = 0; i < 4; ++i)
            xv[i] = *(const float4*)&xs[(i * 32 + ny) * 68 + k4 * 4];
        #pragma unroll
        for (int kk = 0; kk < 4; ++kk) {
            int k = k4 * 4 + kk;
            float w[5];
            #pragma unroll
            for (int j = 0; j < 5; ++j) w[j] = Ws[k * 40 + 5 * cx + j];
            #pragma unroll
            for (int i = 0; i < 4; ++i) {
                float xval = reinterpret_cast<const float*>(&xv[i])[kk];
                #pragma unroll
                for (int j = 0; j < 5; ++j)
                    acc[i][j] = fmaf(xval, w[j], acc[i][j]);
            }
        }
    }

    #pragma unroll
    for (int i = 0; i < 4; ++i) {
        const int node = node0 + i * 32 + ny;
        if (node < n) {
            #pragma unroll
            for (int j = 0; j < 5; ++j)
                out[(size_t)node * 40 + 5 * cx + j] = acc[i][j];
        }
    }
}

extern "C" void kernel_launch(void* const* d_in, const int* in_sizes, int n_in,
                              void* d_out, int out_size, void* d_ws, size_t ws_size,
                              hipStream_t stream) {
    const float* x    = (const float*)d_in[0];
    const int*   ei   = (const int*)d_in[1];
    const float* Win  = (const float*)d_in[2];
    const float* bin  = (const float*)d_in[3];
    const float* wp   = (const float*)d_in[4];
    const float* attw = (const float*)d_in[5];
    const float* attb = (const float*)d_in[6];
    const float* Wout = (const float*)d_in[7];
    const float* bout = (const float*)d_in[8];
    const float* W0   = (const float*)d_in[9];
    const float* b0   = (const float*)d_in[10];
    const float* W1   = (const float*)d_in[11];
    const float* b1   = (const float*)d_in[12];
    const float* W2   = (const float*)d_in[13];
    const float* b2   = (const float*)d_in[14];

    const int N = in_sizes[0] / INC;
    const int E = in_sizes[1] / 2;
    const int* src = ei;
    const int* dst = ei + E;
    float* out = (float*)d_out;

    char* ws = (char*)d_ws;
    size_t off = 0;
    auto alloc = [&](size_t bytes) -> void* {
        void* p = ws + off;
        off = (off + bytes + 255) & ~(size_t)255;
        return p;
    };
    float* A     = (float*)alloc((size_t)N * HID * 4);
    float* Bf    = (float*)alloc((size_t)N * HID * 4);
    float* C     = (float*)alloc((size_t)N * HID * 4);
    float* delta = (float*)alloc((size_t)N * 4);
    float* hwp   = (float*)alloc((size_t)N * 4);
    float* ai    = (float*)alloc((size_t)N * 4);
    float* aj    = (float*)alloc((size_t)N * 4);
    float* pi    = (float*)alloc((size_t)N * 4);
    float* neigh = (float*)alloc((size_t)N * 4);
    float* denom = (float*)alloc((size_t)N * 4);
    float* alpha = (float*)alloc((size_t)E * 4);

    const int tileBlocks64  = (N + 63) / 64;
    const int tileBlocks128 = (N + 127) / 128;
    const int edgeBlocks    = (E + 255) / 256;
    const int scatBlocks    = (int)(((size_t)E * HID + 255) / 256);

    hipMemsetAsync(neigh, 0, (size_t)N * 4, stream);
    hipMemsetAsync(denom, 0, (size_t)N * 4, stream);

    // h0 + per-node reductions
    k_in_gemm<<<tileBlocks64, 256, 0, stream>>>(x, Win, bin, wp, attw,
                                                A, delta, hwp, ai, aj, N);
    // neigh_sum, pi
    k_neigh<<<edgeBlocks, 256, 0, stream>>>(src, dst, delta, neigh, E);
    k_pi<<<(N + 255) / 256, 256, 0, stream>>>(hwp, neigh, pi, N);
    // attention
    k_edge_e<<<edgeBlocks, 256, 0, stream>>>(src, dst, ai, aj, pi, attw, attb,
                                             alpha, denom, E);
    k_alpha<<<edgeBlocks, 256, 0, stream>>>(dst, denom, alpha, E);

    // Layer 0: hl = h0(A) @ W0 + b0 -> Bf ; scatter Bf -> C
    hipMemsetAsync(C, 0, (size_t)N * HID * 4, stream);
    k_gemm64<<<tileBlocks64, 256, 0, stream>>>(A, W0, b0, Bf, N, 0);
    k_scatter<<<scatBlocks, 256, 0, stream>>>(src, dst, alpha, Bf, C, E);

    // Layer 1: hl = relu(C) @ W1 + b1 -> A ; scatter A -> Bf
    k_gemm64<<<tileBlocks64, 256, 0, stream>>>(C, W1, b1, A, N, 1);
    hipMemsetAsync(Bf, 0, (size_t)N * HID * 4, stream);
    k_scatter<<<scatBlocks, 256, 0, stream>>>(src, dst, alpha, A, Bf, E);

    // Layer 2: hl = relu(Bf) @ W2 + b2 -> C ; scatter C -> A
    k_gemm64<<<tileBlocks64, 256, 0, stream>>>(Bf, W2, b2, C, N, 1);
    hipMemsetAsync(A, 0, (size_t)N * HID * 4, stream);
    k_scatter<<<scatBlocks, 256, 0, stream>>>(src, dst, alpha, C, A, E);

    // Output: out = relu(A) @ W_out + b_out
    k_out_gemm<<<tileBlocks128, 256, 0, stream>>>(A, Wout, bout, out, N);
}

// Round 3
// 416.903 us; speedup vs baseline: 2.6367x; 1.8234x over previous
//
#include <hip/hip_runtime.h>
#include <math.h>

// ---------------------------------------------------------------------------
// AGNNet: GAT-like 3-layer GNN. N=100000 nodes, E=800000 edges, HID=64.
// R3: CSR-by-dst build per launch; all segment sums become gathers
// (zero fp32 atomics). GEMMs: LDS-tiled 4x4 register blocking (R2).
// ---------------------------------------------------------------------------

#define HID 64
#define INC 128

// ---------------- CSR build ----------------
__global__ __launch_bounds__(256) void k_degree(
    const int* __restrict__ dst, int* __restrict__ deg, int E)
{
    int e = blockIdx.x * 256 + threadIdx.x;
    if (e < E) atomicAdd(deg + dst[e], 1);
}

// scan1: per-block (1024 elems) exclusive scan of deg -> rowptr, block sums -> bsum
__global__ __launch_bounds__(256) void k_scan1(
    const int* __restrict__ deg, int* __restrict__ rowptr,
    int* __restrict__ bsum, int n)
{
    __shared__ int sdata[256];
    const int t = threadIdx.x;
    const int i0 = blockIdx.x * 1024 + t * 4;
    int v[4];
    #pragma unroll
    for (int j = 0; j < 4; ++j) v[j] = (i0 + j < n) ? deg[i0 + j] : 0;
    int ts = v[0] + v[1] + v[2] + v[3];
    sdata[t] = ts;
    __syncthreads();
    for (int off = 1; off < 256; off <<= 1) {
        int add = (t >= off) ? sdata[t - off] : 0;
        __syncthreads();
        sdata[t] += add;
        __syncthreads();
    }
    int excl = sdata[t] - ts;
    int run = excl;
    #pragma unroll
    for (int j = 0; j < 4; ++j) {
        if (i0 + j < n) rowptr[i0 + j] = run;
        run += v[j];
    }
    if (t == 255) bsum[blockIdx.x] = sdata[255];
}

// scan2: single block exclusive scan of bsum (B <= 128)
__global__ __launch_bounds__(128) void k_scan2(int* __restrict__ bsum, int B)
{
    __shared__ int sdata[128];
    const int t = threadIdx.x;
    int v = (t < B) ? bsum[t] : 0;
    sdata[t] = v;
    __syncthreads();
    for (int off = 1; off < 128; off <<= 1) {
        int add = (t >= off) ? sdata[t - off] : 0;
        __syncthreads();
        sdata[t] += add;
        __syncthreads();
    }
    if (t < B) bsum[t] = sdata[t] - v;
}

// scan3: rowptr[i] += bsum[blk]; cursor = rowptr; rowptr[n] = E
__global__ __launch_bounds__(256) void k_scan3(
    int* __restrict__ rowptr, int* __restrict__ cursor,
    const int* __restrict__ bsum, int n, int E)
{
    const int t = threadIdx.x;
    const int i0 = blockIdx.x * 1024 + t * 4;
    const int add = bsum[blockIdx.x];
    #pragma unroll
    for (int j = 0; j < 4; ++j) {
        int i = i0 + j;
        if (i < n) {
            int r = rowptr[i] + add;
            rowptr[i] = r;
            cursor[i] = r;
        }
    }
    if (blockIdx.x == 0 && t == 0) rowptr[n] = E;
}

__global__ __launch_bounds__(256) void k_place(
    const int* __restrict__ src, const int* __restrict__ dst,
    int* __restrict__ cursor, int* __restrict__ csr_src, int E)
{
    int e = blockIdx.x * 256 + threadIdx.x;
    if (e < E) {
        int slot = atomicAdd(cursor + dst[e], 1);
        csr_src[slot] = src[e];
    }
}

// ---------------- Node-feature kernels ----------------
// h0 = relu(x @ W_in + b_in); fused: delta=sum|h0|, hwp=h0.wp, ai=h0.w_i, aj=h0.w_j
__global__ __launch_bounds__(256) void k_in_gemm(
    const float* __restrict__ x, const float* __restrict__ Win,
    const float* __restrict__ bin, const float* __restrict__ wp,
    const float* __restrict__ attw,
    float* __restrict__ h0, float* __restrict__ delta, float* __restrict__ hwp,
    float* __restrict__ ai, float* __restrict__ aj, int n)
{
    __shared__ float xs[64 * 132];
    __shared__ float Ws[INC * HID];
    const int t = threadIdx.x;
    const int node0 = blockIdx.x * 64;

    #pragma unroll
    for (int p = 0; p < 8; ++p) {
        int c = t + p * 256;
        *(float4*)&Ws[c * 4] = *(const float4*)&Win[c * 4];
    }
    #pragma unroll
    for (int p = 0; p < 8; ++p) {
        int c = t + p * 256;
        int row = c >> 5;
        int col = (c & 31) * 4;
        float4 v = make_float4(0.f, 0.f, 0.f, 0.f);
        if (node0 + row < n) v = *(const float4*)&x[(size_t)(node0 + row) * INC + col];
        *(float4*)&xs[row * 132 + col] = v;
    }
    __syncthreads();

    const int cx = t & 15;
    const int ny = t >> 4;
    float acc[4][4];
    const float4 bv = *(const float4*)&bin[cx * 4];
    #pragma unroll
    for (int i = 0; i < 4; ++i) {
        acc[i][0] = bv.x; acc[i][1] = bv.y; acc[i][2] = bv.z; acc[i][3] = bv.w;
    }

    #pragma unroll 4
    for (int k4 = 0; k4 < 32; ++k4) {
        float4 xv[4];
        #pragma unroll
        for (int i = 0; i < 4; ++i)
            xv[i] = *(const float4*)&xs[(i * 16 + ny) * 132 + k4 * 4];
        #pragma unroll
        for (int kk = 0; kk < 4; ++kk) {
            float4 w = *(const float4*)&Ws[(k4 * 4 + kk) * HID + cx * 4];
            #pragma unroll
            for (int i = 0; i < 4; ++i) {
                float xval = reinterpret_cast<const float*>(&xv[i])[kk];
                acc[i][0] = fmaf(xval, w.x, acc[i][0]);
                acc[i][1] = fmaf(xval, w.y, acc[i][1]);
                acc[i][2] = fmaf(xval, w.z, acc[i][2]);
                acc[i][3] = fmaf(xval, w.w, acc[i][3]);
            }
        }
    }

    const float4 wpv = *(const float4*)&wp[cx * 4];
    const float4 wiv = *(const float4*)&attw[cx * 4];
    const float4 wjv = *(const float4*)&attw[HID + cx * 4];

    #pragma unroll
    for (int i = 0; i < 4; ++i) {
        const int node = node0 + i * 16 + ny;
        float h0v = fmaxf(acc[i][0], 0.f);
        float h1v = fmaxf(acc[i][1], 0.f);
        float h2v = fmaxf(acc[i][2], 0.f);
        float h3v = fmaxf(acc[i][3], 0.f);
        if (node < n) {
            float4 hv = make_float4(h0v, h1v, h2v, h3v);
            *(float4*)&h0[(size_t)node * HID + cx * 4] = hv;
        }
        float vd = h0v + h1v + h2v + h3v;
        float vw = h0v * wpv.x + h1v * wpv.y + h2v * wpv.z + h3v * wpv.w;
        float vi = h0v * wiv.x + h1v * wiv.y + h2v * wiv.z + h3v * wiv.w;
        float vj = h0v * wjv.x + h1v * wjv.y + h2v * wjv.z + h3v * wjv.w;
        #pragma unroll
        for (int m = 1; m < 16; m <<= 1) {
            vd += __shfl_xor(vd, m);
            vw += __shfl_xor(vw, m);
            vi += __shfl_xor(vi, m);
            vj += __shfl_xor(vj, m);
        }
        if (cx == 0 && node < n) {
            delta[node] = vd; hwp[node] = vw; ai[node] = vi; aj[node] = vj;
        }
    }
}

// neigh_sum (CSR gather) fused with pi = sigmoid(hwp + neigh)
__global__ __launch_bounds__(256) void k_neigh_pi(
    const int* __restrict__ rowptr, const int* __restrict__ csr_src,
    const float* __restrict__ delta, const float* __restrict__ hwp,
    float* __restrict__ pi, int n)
{
    int i = blockIdx.x * 256 + threadIdx.x;
    if (i >= n) return;
    int p0 = rowptr[i], p1 = rowptr[i + 1];
    float s = 0.f;
    for (int p = p0; p < p1; ++p) s += delta[csr_src[p]];
    float v = hwp[i] + s;
    pi[i] = 1.f / (1.f + expf(-v));
}

// attention: alpha_csr (exp of lrelu, normalized per row)
__global__ __launch_bounds__(256) void k_att(
    const int* __restrict__ rowptr, const int* __restrict__ csr_src,
    const float* __restrict__ ai, const float* __restrict__ aj,
    const float* __restrict__ pi, const float* __restrict__ attw,
    const float* __restrict__ attb,
    float* __restrict__ alpha_csr, int n)
{
    int i = blockIdx.x * 256 + threadIdx.x;
    if (i >= n) return;
    const float wpe = attw[2 * HID];
    const float ab  = attb[0];
    int p0 = rowptr[i], p1 = rowptr[i + 1];
    float aid = ai[i];
    float den = 0.f;
    for (int p = p0; p < p1; ++p) {
        int s = csr_src[p];
        float v = aid + aj[s] + pi[s] * wpe + ab;
        v = v > 0.f ? v : 0.2f * v;
        float ev = expf(v);
        alpha_csr[p] = ev;
        den += ev;
    }
    float inv = 1.f / (den + 1e-16f);
    for (int p = p0; p < p1; ++p) alpha_csr[p] *= inv;
}

// ---------------- GEMMs ----------------
__global__ __launch_bounds__(256) void k_gemm64(
    const float* __restrict__ hin, const float* __restrict__ W,
    const float* __restrict__ b, float* __restrict__ hout, int n, int relu_in)
{
    __shared__ float xs[64 * 68];
    __shared__ float Ws[HID * HID];
    const int t = threadIdx.x;
    const int node0 = blockIdx.x * 64;

    #pragma unroll
    for (int p = 0; p < 4; ++p) {
        int c = t + p * 256;
        *(float4*)&Ws[c * 4] = *(const float4*)&W[c * 4];
    }
    #pragma unroll
    for (int p = 0; p < 4; ++p) {
        int c = t + p * 256;
        int row = c >> 4;
        int col = (c & 15) * 4;
        float4 v = make_float4(0.f, 0.f, 0.f, 0.f);
        if (node0 + row < n) v = *(const float4*)&hin[(size_t)(node0 + row) * HID + col];
        if (relu_in) {
            v.x = fmaxf(v.x, 0.f); v.y = fmaxf(v.y, 0.f);
            v.z = fmaxf(v.z, 0.f); v.w = fmaxf(v.w, 0.f);
        }
        *(float4*)&xs[row * 68 + col] = v;
    }
    __syncthreads();

    const int cx = t & 15;
    const int ny = t >> 4;
    float acc[4][4];
    const float4 bv = *(const float4*)&b[cx * 4];
    #pragma unroll
    for (int i = 0; i < 4; ++i) {
        acc[i][0] = bv.x; acc[i][1] = bv.y; acc[i][2] = bv.z; acc[i][3] = bv.w;
    }

    #pragma unroll 4
    for (int k4 = 0; k4 < 16; ++k4) {
        float4 xv[4];
        #pragma unroll
        for (int i = 0; i < 4; ++i)
            xv[i] = *(const float4*)&xs[(i * 16 + ny) * 68 + k4 * 4];
        #pragma unroll
        for (int kk = 0; kk < 4; ++kk) {
            float4 w = *(const float4*)&Ws[(k4 * 4 + kk) * HID + cx * 4];
            #pragma unroll
            for (int i = 0; i < 4; ++i) {
                float xval = reinterpret_cast<const float*>(&xv[i])[kk];
                acc[i][0] = fmaf(xval, w.x, acc[i][0]);
                acc[i][1] = fmaf(xval, w.y, acc[i][1]);
                acc[i][2] = fmaf(xval, w.z, acc[i][2]);
                acc[i][3] = fmaf(xval, w.w, acc[i][3]);
            }
        }
    }

    #pragma unroll
    for (int i = 0; i < 4; ++i) {
        const int node = node0 + i * 16 + ny;
        if (node < n) {
            float4 hv = make_float4(acc[i][0], acc[i][1], acc[i][2], acc[i][3]);
            *(float4*)&hout[(size_t)node * HID + cx * 4] = hv;
        }
    }
}

// aggregation gather: out[d][c] = sum_p alpha[p] * hl[csr_src[p]][c]
// wave per node, lane = channel
__global__ __launch_bounds__(256) void k_gather(
    const int* __restrict__ rowptr, const int* __restrict__ csr_src,
    const float* __restrict__ alpha_csr, const float* __restrict__ hl,
    float* __restrict__ out, int n)
{
    const int wave = threadIdx.x >> 6;
    const int lane = threadIdx.x & 63;
    const int node = blockIdx.x * 4 + wave;
    if (node >= n) return;

    const int p0 = rowptr[node], p1 = rowptr[node + 1];
    float acc = 0.f;
    for (int base = p0; base < p1; base += 64) {
        int m = p1 - base; if (m > 64) m = 64;
        float a_l = 0.f; int s_l = 0;
        if (lane < m) { a_l = alpha_csr[base + lane]; s_l = csr_src[base + lane]; }
        for (int j = 0; j < m; ++j) {
            float a = __shfl(a_l, j);
            int   s = __shfl(s_l, j);
            acc = fmaf(a, hl[(size_t)s * HID + lane], acc);
        }
    }
    out[(size_t)node * HID + lane] = acc;
}

// out = relu(h) @ W_out + b_out  (64x40), tile 128 nodes
__global__ __launch_bounds__(256) void k_out_gemm(
    const float* __restrict__ hin, const float* __restrict__ W,
    const float* __restrict__ b, float* __restrict__ out, int n)
{
    __shared__ float xs[128 * 68];
    __shared__ float Ws[HID * 40];
    const int t = threadIdx.x;
    const int node0 = blockIdx.x * 128;

    #pragma unroll
    for (int p = 0; p < 3; ++p) {
        int c = t + p * 256;
        if (c < 640) *(float4*)&Ws[c * 4] = *(const float4*)&W[c * 4];
    }
    #pragma unroll
    for (int p = 0; p < 8; ++p) {
        int c = t + p * 256;
        int row = c >> 4;
        int col = (c & 15) * 4;
        float4 v = make_float4(0.f, 0.f, 0.f, 0.f);
        if (node0 + row < n) v = *(const float4*)&hin[(size_t)(node0 + row) * HID + col];
        v.x = fmaxf(v.x, 0.f); v.y = fmaxf(v.y, 0.f);
        v.z = fmaxf(v.z, 0.f); v.w = fmaxf(v.w, 0.f);
        *(float4*)&xs[row * 68 + col] = v;
    }
    __syncthreads();

    const int cx = t & 7;
    const int ny = t >> 3;
    float acc[4][5];
    #pragma unroll
    for (int j = 0; j < 5; ++j) {
        float bj = b[5 * cx + j];
        #pragma unroll
        for (int i = 0; i < 4; ++i) acc[i][j] = bj;
    }

    #pragma unroll 4
    for (int k4 = 0; k4 < 16; ++k4) {
        float4 xv[4];
        #pragma unroll
        for (int i = 0; i < 4; ++i)
            xv[i] = *(const float4*)&xs[(i * 32 + ny) * 68 + k4 * 4];
        #pragma unroll
        for (int kk = 0; kk < 4; ++kk) {
            int k = k4 * 4 + kk;
            float w[5];
            #pragma unroll
            for (int j = 0; j < 5; ++j) w[j] = Ws[k * 40 + 5 * cx + j];
            #pragma unroll
            for (int i = 0; i < 4; ++i) {
                float xval = reinterpret_cast<const float*>(&xv[i])[kk];
                #pragma unroll
                for (int j = 0; j < 5; ++j)
                    acc[i][j] = fmaf(xval, w[j], acc[i][j]);
            }
        }
    }

    #pragma unroll
    for (int i = 0; i < 4; ++i) {
        const int node = node0 + i * 32 + ny;
        if (node < n) {
            #pragma unroll
            for (int j = 0; j < 5; ++j)
                out[(size_t)node * 40 + 5 * cx + j] = acc[i][j];
        }
    }
}

extern "C" void kernel_launch(void* const* d_in, const int* in_sizes, int n_in,
                              void* d_out, int out_size, void* d_ws, size_t ws_size,
                              hipStream_t stream) {
    const float* x    = (const float*)d_in[0];
    const int*   ei   = (const int*)d_in[1];
    const float* Win  = (const float*)d_in[2];
    const float* bin  = (const float*)d_in[3];
    const float* wp   = (const float*)d_in[4];
    const float* attw = (const float*)d_in[5];
    const float* attb = (const float*)d_in[6];
    const float* Wout = (const float*)d_in[7];
    const float* bout = (const float*)d_in[8];
    const float* W0   = (const float*)d_in[9];
    const float* b0   = (const float*)d_in[10];
    const float* W1   = (const float*)d_in[11];
    const float* b1   = (const float*)d_in[12];
    const float* W2   = (const float*)d_in[13];
    const float* b2   = (const float*)d_in[14];

    const int N = in_sizes[0] / INC;
    const int E = in_sizes[1] / 2;
    const int* src = ei;
    const int* dst = ei + E;
    float* out = (float*)d_out;

    char* ws = (char*)d_ws;
    size_t off = 0;
    auto alloc = [&](size_t bytes) -> void* {
        void* p = ws + off;
        off = (off + bytes + 255) & ~(size_t)255;
        return p;
    };
    float* A       = (float*)alloc((size_t)N * HID * 4);
    float* Bf      = (float*)alloc((size_t)N * HID * 4);
    float* C       = (float*)alloc((size_t)N * HID * 4);
    float* delta   = (float*)alloc((size_t)N * 4);
    float* hwp     = (float*)alloc((size_t)N * 4);
    float* ai      = (float*)alloc((size_t)N * 4);
    float* aj      = (float*)alloc((size_t)N * 4);
    float* pi      = (float*)alloc((size_t)N * 4);
    int*   deg     = (int*)alloc((size_t)N * 4);
    int*   rowptr  = (int*)alloc((size_t)(N + 1) * 4);
    int*   cursor  = (int*)alloc((size_t)N * 4);
    int*   bsum    = (int*)alloc(256 * 4);
    int*   csr_src = (int*)alloc((size_t)E * 4);
    float* alpha   = (float*)alloc((size_t)E * 4);

    const int tileBlocks64  = (N + 63) / 64;
    const int tileBlocks128 = (N + 127) / 128;
    const int edgeBlocks    = (E + 255) / 256;
    const int nodeBlocks256 = (N + 255) / 256;
    const int nodeBlocksW   = (N + 3) / 4;       // wave-per-node
    const int scanBlocks    = (N + 1023) / 1024; // 98

    // ---- CSR build ----
    hipMemsetAsync(deg, 0, (size_t)N * 4, stream);
    k_degree<<<edgeBlocks, 256, 0, stream>>>(dst, deg, E);
    k_scan1<<<scanBlocks, 256, 0, stream>>>(deg, rowptr, bsum, N);
    k_scan2<<<1, 128, 0, stream>>>(bsum, scanBlocks);
    k_scan3<<<scanBlocks, 256, 0, stream>>>(rowptr, cursor, bsum, N, E);
    k_place<<<edgeBlocks, 256, 0, stream>>>(src, dst, cursor, csr_src, E);

    // ---- node features + attention ----
    k_in_gemm<<<tileBlocks64, 256, 0, stream>>>(x, Win, bin, wp, attw,
                                                A, delta, hwp, ai, aj, N);
    k_neigh_pi<<<nodeBlocks256, 256, 0, stream>>>(rowptr, csr_src, delta, hwp, pi, N);
    k_att<<<nodeBlocks256, 256, 0, stream>>>(rowptr, csr_src, ai, aj, pi,
                                             attw, attb, alpha, N);

    // ---- layers ----
    k_gemm64<<<tileBlocks64, 256, 0, stream>>>(A, W0, b0, Bf, N, 0);
    k_gather<<<nodeBlocksW, 256, 0, stream>>>(rowptr, csr_src, alpha, Bf, C, N);

    k_gemm64<<<tileBlocks64, 256, 0, stream>>>(C, W1, b1, A, N, 1);
    k_gather<<<nodeBlocksW, 256, 0, stream>>>(rowptr, csr_src, alpha, A, Bf, N);

    k_gemm64<<<tileBlocks64, 256, 0, stream>>>(Bf, W2, b2, C, N, 1);
    k_gather<<<nodeBlocksW, 256, 0, stream>>>(rowptr, csr_src, alpha, C, A, N);

    k_out_gemm<<<tileBlocks128, 256, 0, stream>>>(A, Wout, bout, out, N);
}

// Round 4
// 347.479 us; speedup vs baseline: 3.1634x; 1.1998x over previous
//
#include <hip/hip_runtime.h>
#include <math.h>

// ---------------------------------------------------------------------------
// AGNNet: GAT-like 3-layer GNN. N=100000 nodes, E=800000 edges, HID=64.
// R4: gather rewritten: 4 edge-groups x 16 lanes x float4 -> 4 edges in
// flight per wave, 4x fewer load instructions. Rest as R3.
// ---------------------------------------------------------------------------

#define HID 64
#define INC 128

// ---------------- CSR build ----------------
__global__ __launch_bounds__(256) void k_degree(
    const int* __restrict__ dst, int* __restrict__ deg, int E)
{
    int e = blockIdx.x * 256 + threadIdx.x;
    if (e < E) atomicAdd(deg + dst[e], 1);
}

__global__ __launch_bounds__(256) void k_scan1(
    const int* __restrict__ deg, int* __restrict__ rowptr,
    int* __restrict__ bsum, int n)
{
    __shared__ int sdata[256];
    const int t = threadIdx.x;
    const int i0 = blockIdx.x * 1024 + t * 4;
    int v[4];
    #pragma unroll
    for (int j = 0; j < 4; ++j) v[j] = (i0 + j < n) ? deg[i0 + j] : 0;
    int ts = v[0] + v[1] + v[2] + v[3];
    sdata[t] = ts;
    __syncthreads();
    for (int off = 1; off < 256; off <<= 1) {
        int add = (t >= off) ? sdata[t - off] : 0;
        __syncthreads();
        sdata[t] += add;
        __syncthreads();
    }
    int excl = sdata[t] - ts;
    int run = excl;
    #pragma unroll
    for (int j = 0; j < 4; ++j) {
        if (i0 + j < n) rowptr[i0 + j] = run;
        run += v[j];
    }
    if (t == 255) bsum[blockIdx.x] = sdata[255];
}

__global__ __launch_bounds__(128) void k_scan2(int* __restrict__ bsum, int B)
{
    __shared__ int sdata[128];
    const int t = threadIdx.x;
    int v = (t < B) ? bsum[t] : 0;
    sdata[t] = v;
    __syncthreads();
    for (int off = 1; off < 128; off <<= 1) {
        int add = (t >= off) ? sdata[t - off] : 0;
        __syncthreads();
        sdata[t] += add;
        __syncthreads();
    }
    if (t < B) bsum[t] = sdata[t] - v;
}

__global__ __launch_bounds__(256) void k_scan3(
    int* __restrict__ rowptr, int* __restrict__ cursor,
    const int* __restrict__ bsum, int n, int E)
{
    const int t = threadIdx.x;
    const int i0 = blockIdx.x * 1024 + t * 4;
    const int add = bsum[blockIdx.x];
    #pragma unroll
    for (int j = 0; j < 4; ++j) {
        int i = i0 + j;
        if (i < n) {
            int r = rowptr[i] + add;
            rowptr[i] = r;
            cursor[i] = r;
        }
    }
    if (blockIdx.x == 0 && t == 0) rowptr[n] = E;
}

__global__ __launch_bounds__(256) void k_place(
    const int* __restrict__ src, const int* __restrict__ dst,
    int* __restrict__ cursor, int* __restrict__ csr_src, int E)
{
    int e = blockIdx.x * 256 + threadIdx.x;
    if (e < E) {
        int slot = atomicAdd(cursor + dst[e], 1);
        csr_src[slot] = src[e];
    }
}

// ---------------- Node-feature kernels ----------------
__global__ __launch_bounds__(256) void k_in_gemm(
    const float* __restrict__ x, const float* __restrict__ Win,
    const float* __restrict__ bin, const float* __restrict__ wp,
    const float* __restrict__ attw,
    float* __restrict__ h0, float* __restrict__ delta, float* __restrict__ hwp,
    float* __restrict__ ai, float* __restrict__ aj, int n)
{
    __shared__ float xs[64 * 132];
    __shared__ float Ws[INC * HID];
    const int t = threadIdx.x;
    const int node0 = blockIdx.x * 64;

    #pragma unroll
    for (int p = 0; p < 8; ++p) {
        int c = t + p * 256;
        *(float4*)&Ws[c * 4] = *(const float4*)&Win[c * 4];
    }
    #pragma unroll
    for (int p = 0; p < 8; ++p) {
        int c = t + p * 256;
        int row = c >> 5;
        int col = (c & 31) * 4;
        float4 v = make_float4(0.f, 0.f, 0.f, 0.f);
        if (node0 + row < n) v = *(const float4*)&x[(size_t)(node0 + row) * INC + col];
        *(float4*)&xs[row * 132 + col] = v;
    }
    __syncthreads();

    const int cx = t & 15;
    const int ny = t >> 4;
    float acc[4][4];
    const float4 bv = *(const float4*)&bin[cx * 4];
    #pragma unroll
    for (int i = 0; i < 4; ++i) {
        acc[i][0] = bv.x; acc[i][1] = bv.y; acc[i][2] = bv.z; acc[i][3] = bv.w;
    }

    #pragma unroll 4
    for (int k4 = 0; k4 < 32; ++k4) {
        float4 xv[4];
        #pragma unroll
        for (int i = 0; i < 4; ++i)
            xv[i] = *(const float4*)&xs[(i * 16 + ny) * 132 + k4 * 4];
        #pragma unroll
        for (int kk = 0; kk < 4; ++kk) {
            float4 w = *(const float4*)&Ws[(k4 * 4 + kk) * HID + cx * 4];
            #pragma unroll
            for (int i = 0; i < 4; ++i) {
                float xval = reinterpret_cast<const float*>(&xv[i])[kk];
                acc[i][0] = fmaf(xval, w.x, acc[i][0]);
                acc[i][1] = fmaf(xval, w.y, acc[i][1]);
                acc[i][2] = fmaf(xval, w.z, acc[i][2]);
                acc[i][3] = fmaf(xval, w.w, acc[i][3]);
            }
        }
    }

    const float4 wpv = *(const float4*)&wp[cx * 4];
    const float4 wiv = *(const float4*)&attw[cx * 4];
    const float4 wjv = *(const float4*)&attw[HID + cx * 4];

    #pragma unroll
    for (int i = 0; i < 4; ++i) {
        const int node = node0 + i * 16 + ny;
        float h0v = fmaxf(acc[i][0], 0.f);
        float h1v = fmaxf(acc[i][1], 0.f);
        float h2v = fmaxf(acc[i][2], 0.f);
        float h3v = fmaxf(acc[i][3], 0.f);
        if (node < n) {
            float4 hv = make_float4(h0v, h1v, h2v, h3v);
            *(float4*)&h0[(size_t)node * HID + cx * 4] = hv;
        }
        float vd = h0v + h1v + h2v + h3v;
        float vw = h0v * wpv.x + h1v * wpv.y + h2v * wpv.z + h3v * wpv.w;
        float vi = h0v * wiv.x + h1v * wiv.y + h2v * wiv.z + h3v * wiv.w;
        float vj = h0v * wjv.x + h1v * wjv.y + h2v * wjv.z + h3v * wjv.w;
        #pragma unroll
        for (int m = 1; m < 16; m <<= 1) {
            vd += __shfl_xor(vd, m);
            vw += __shfl_xor(vw, m);
            vi += __shfl_xor(vi, m);
            vj += __shfl_xor(vj, m);
        }
        if (cx == 0 && node < n) {
            delta[node] = vd; hwp[node] = vw; ai[node] = vi; aj[node] = vj;
        }
    }
}

__global__ __launch_bounds__(256) void k_neigh_pi(
    const int* __restrict__ rowptr, const int* __restrict__ csr_src,
    const float* __restrict__ delta, const float* __restrict__ hwp,
    float* __restrict__ pi, int n)
{
    int i = blockIdx.x * 256 + threadIdx.x;
    if (i >= n) return;
    int p0 = rowptr[i], p1 = rowptr[i + 1];
    float s = 0.f;
    for (int p = p0; p < p1; ++p) s += delta[csr_src[p]];
    float v = hwp[i] + s;
    pi[i] = 1.f / (1.f + expf(-v));
}

__global__ __launch_bounds__(256) void k_att(
    const int* __restrict__ rowptr, const int* __restrict__ csr_src,
    const float* __restrict__ ai, const float* __restrict__ aj,
    const float* __restrict__ pi, const float* __restrict__ attw,
    const float* __restrict__ attb,
    float* __restrict__ alpha_csr, int n)
{
    int i = blockIdx.x * 256 + threadIdx.x;
    if (i >= n) return;
    const float wpe = attw[2 * HID];
    const float ab  = attb[0];
    int p0 = rowptr[i], p1 = rowptr[i + 1];
    float aid = ai[i];
    float den = 0.f;
    for (int p = p0; p < p1; ++p) {
        int s = csr_src[p];
        float v = aid + aj[s] + pi[s] * wpe + ab;
        v = v > 0.f ? v : 0.2f * v;
        float ev = expf(v);
        alpha_csr[p] = ev;
        den += ev;
    }
    float inv = 1.f / (den + 1e-16f);
    for (int p = p0; p < p1; ++p) alpha_csr[p] *= inv;
}

// ---------------- GEMMs ----------------
__global__ __launch_bounds__(256) void k_gemm64(
    const float* __restrict__ hin, const float* __restrict__ W,
    const float* __restrict__ b, float* __restrict__ hout, int n, int relu_in)
{
    __shared__ float xs[64 * 68];
    __shared__ float Ws[HID * HID];
    const int t = threadIdx.x;
    const int node0 = blockIdx.x * 64;

    #pragma unroll
    for (int p = 0; p < 4; ++p) {
        int c = t + p * 256;
        *(float4*)&Ws[c * 4] = *(const float4*)&W[c * 4];
    }
    #pragma unroll
    for (int p = 0; p < 4; ++p) {
        int c = t + p * 256;
        int row = c >> 4;
        int col = (c & 15) * 4;
        float4 v = make_float4(0.f, 0.f, 0.f, 0.f);
        if (node0 + row < n) v = *(const float4*)&hin[(size_t)(node0 + row) * HID + col];
        if (relu_in) {
            v.x = fmaxf(v.x, 0.f); v.y = fmaxf(v.y, 0.f);
            v.z = fmaxf(v.z, 0.f); v.w = fmaxf(v.w, 0.f);
        }
        *(float4*)&xs[row * 68 + col] = v;
    }
    __syncthreads();

    const int cx = t & 15;
    const int ny = t >> 4;
    float acc[4][4];
    const float4 bv = *(const float4*)&b[cx * 4];
    #pragma unroll
    for (int i = 0; i < 4; ++i) {
        acc[i][0] = bv.x; acc[i][1] = bv.y; acc[i][2] = bv.z; acc[i][3] = bv.w;
    }

    #pragma unroll 4
    for (int k4 = 0; k4 < 16; ++k4) {
        float4 xv[4];
        #pragma unroll
        for (int i = 0; i < 4; ++i)
            xv[i] = *(const float4*)&xs[(i * 16 + ny) * 68 + k4 * 4];
        #pragma unroll
        for (int kk = 0; kk < 4; ++kk) {
            float4 w = *(const float4*)&Ws[(k4 * 4 + kk) * HID + cx * 4];
            #pragma unroll
            for (int i = 0; i < 4; ++i) {
                float xval = reinterpret_cast<const float*>(&xv[i])[kk];
                acc[i][0] = fmaf(xval, w.x, acc[i][0]);
                acc[i][1] = fmaf(xval, w.y, acc[i][1]);
                acc[i][2] = fmaf(xval, w.z, acc[i][2]);
                acc[i][3] = fmaf(xval, w.w, acc[i][3]);
            }
        }
    }

    #pragma unroll
    for (int i = 0; i < 4; ++i) {
        const int node = node0 + i * 16 + ny;
        if (node < n) {
            float4 hv = make_float4(acc[i][0], acc[i][1], acc[i][2], acc[i][3]);
            *(float4*)&hout[(size_t)node * HID + cx * 4] = hv;
        }
    }
}

// gather: out[d][:] = sum_p alpha[p] * hl[csr_src[p]][:]
// wave per node; 4 edge-groups x 16 lanes x float4 -> 4 edges in flight.
__global__ __launch_bounds__(256) void k_gather(
    const int* __restrict__ rowptr, const int* __restrict__ csr_src,
    const float* __restrict__ alpha_csr, const float* __restrict__ hl,
    float* __restrict__ out, int n)
{
    const int wave = threadIdx.x >> 6;
    const int lane = threadIdx.x & 63;
    const int g    = lane >> 4;        // edge-group 0..3
    const int q    = lane & 15;        // channel quad
    const int node = blockIdx.x * 4 + wave;
    if (node >= n) return;

    const int p0 = rowptr[node], p1 = rowptr[node + 1];
    float4 acc = make_float4(0.f, 0.f, 0.f, 0.f);

    for (int base = p0; base < p1; base += 64) {
        int m = p1 - base; if (m > 64) m = 64;
        float a_l = 0.f; int s_l = 0;
        if (lane < m) { a_l = alpha_csr[base + lane]; s_l = csr_src[base + lane]; }
        for (int j = 0; j < m; j += 4) {
            const int e = j + g;
            float a = __shfl(a_l, e);
            int   s = __shfl(s_l, e);
            if (e < m) {
                float4 v = *(const float4*)&hl[(size_t)s * HID + q * 4];
                acc.x = fmaf(a, v.x, acc.x);
                acc.y = fmaf(a, v.y, acc.y);
                acc.z = fmaf(a, v.z, acc.z);
                acc.w = fmaf(a, v.w, acc.w);
            }
        }
    }
    // combine across the 4 edge-groups
    #pragma unroll
    for (int m2 = 16; m2 <= 32; m2 <<= 1) {
        acc.x += __shfl_xor(acc.x, m2);
        acc.y += __shfl_xor(acc.y, m2);
        acc.z += __shfl_xor(acc.z, m2);
        acc.w += __shfl_xor(acc.w, m2);
    }
    if (g == 0)
        *(float4*)&out[(size_t)node * HID + q * 4] = acc;
}

__global__ __launch_bounds__(256) void k_out_gemm(
    const float* __restrict__ hin, const float* __restrict__ W,
    const float* __restrict__ b, float* __restrict__ out, int n)
{
    __shared__ float xs[128 * 68];
    __shared__ float Ws[HID * 40];
    const int t = threadIdx.x;
    const int node0 = blockIdx.x * 128;

    #pragma unroll
    for (int p = 0; p < 3; ++p) {
        int c = t + p * 256;
        if (c < 640) *(float4*)&Ws[c * 4] = *(const float4*)&W[c * 4];
    }
    #pragma unroll
    for (int p = 0; p < 8; ++p) {
        int c = t + p * 256;
        int row = c >> 4;
        int col = (c & 15) * 4;
        float4 v = make_float4(0.f, 0.f, 0.f, 0.f);
        if (node0 + row < n) v = *(const float4*)&hin[(size_t)(node0 + row) * HID + col];
        v.x = fmaxf(v.x, 0.f); v.y = fmaxf(v.y, 0.f);
        v.z = fmaxf(v.z, 0.f); v.w = fmaxf(v.w, 0.f);
        *(float4*)&xs[row * 68 + col] = v;
    }
    __syncthreads();

    const int cx = t & 7;
    const int ny = t >> 3;
    float acc[4][5];
    #pragma unroll
    for (int j = 0; j < 5; ++j) {
        float bj = b[5 * cx + j];
        #pragma unroll
        for (int i = 0; i < 4; ++i) acc[i][j] = bj;
    }

    #pragma unroll 4
    for (int k4 = 0; k4 < 16; ++k4) {
        float4 xv[4];
        #pragma unroll
        for (int i = 0; i < 4; ++i)
            xv[i] = *(const float4*)&xs[(i * 32 + ny) * 68 + k4 * 4];
        #pragma unroll
        for (int kk = 0; kk < 4; ++kk) {
            int k = k4 * 4 + kk;
            float w[5];
            #pragma unroll
            for (int j = 0; j < 5; ++j) w[j] = Ws[k * 40 + 5 * cx + j];
            #pragma unroll
            for (int i = 0; i < 4; ++i) {
                float xval = reinterpret_cast<const float*>(&xv[i])[kk];
                #pragma unroll
                for (int j = 0; j < 5; ++j)
                    acc[i][j] = fmaf(xval, w[j], acc[i][j]);
            }
        }
    }

    #pragma unroll
    for (int i = 0; i < 4; ++i) {
        const int node = node0 + i * 32 + ny;
        if (node < n) {
            #pragma unroll
            for (int j = 0; j < 5; ++j)
                out[(size_t)node * 40 + 5 * cx + j] = acc[i][j];
        }
    }
}

extern "C" void kernel_launch(void* const* d_in, const int* in_sizes, int n_in,
                              void* d_out, int out_size, void* d_ws, size_t ws_size,
                              hipStream_t stream) {
    const float* x    = (const float*)d_in[0];
    const int*   ei   = (const int*)d_in[1];
    const float* Win  = (const float*)d_in[2];
    const float* bin  = (const float*)d_in[3];
    const float* wp   = (const float*)d_in[4];
    const float* attw = (const float*)d_in[5];
    const float* attb = (const float*)d_in[6];
    const float* Wout = (const float*)d_in[7];
    const float* bout = (const float*)d_in[8];
    const float* W0   = (const float*)d_in[9];
    const float* b0   = (const float*)d_in[10];
    const float* W1   = (const float*)d_in[11];
    const float* b1   = (const float*)d_in[12];
    const float* W2   = (const float*)d_in[13];
    const float* b2   = (const float*)d_in[14];

    const int N = in_sizes[0] / INC;
    const int E = in_sizes[1] / 2;
    const int* src = ei;
    const int* dst = ei + E;
    float* out = (float*)d_out;

    char* ws = (char*)d_ws;
    size_t off = 0;
    auto alloc = [&](size_t bytes) -> void* {
        void* p = ws + off;
        off = (off + bytes + 255) & ~(size_t)255;
        return p;
    };
    float* A       = (float*)alloc((size_t)N * HID * 4);
    float* Bf      = (float*)alloc((size_t)N * HID * 4);
    float* C       = (float*)alloc((size_t)N * HID * 4);
    float* delta   = (float*)alloc((size_t)N * 4);
    float* hwp     = (float*)alloc((size_t)N * 4);
    float* ai      = (float*)alloc((size_t)N * 4);
    float* aj      = (float*)alloc((size_t)N * 4);
    float* pi      = (float*)alloc((size_t)N * 4);
    int*   deg     = (int*)alloc((size_t)N * 4);
    int*   rowptr  = (int*)alloc((size_t)(N + 1) * 4);
    int*   cursor  = (int*)alloc((size_t)N * 4);
    int*   bsum    = (int*)alloc(256 * 4);
    int*   csr_src = (int*)alloc((size_t)E * 4);
    float* alpha   = (float*)alloc((size_t)E * 4);

    const int tileBlocks64  = (N + 63) / 64;
    const int tileBlocks128 = (N + 127) / 128;
    const int edgeBlocks    = (E + 255) / 256;
    const int nodeBlocks256 = (N + 255) / 256;
    const int nodeBlocksW   = (N + 3) / 4;
    const int scanBlocks    = (N + 1023) / 1024;

    // ---- CSR build ----
    hipMemsetAsync(deg, 0, (size_t)N * 4, stream);
    k_degree<<<edgeBlocks, 256, 0, stream>>>(dst, deg, E);
    k_scan1<<<scanBlocks, 256, 0, stream>>>(deg, rowptr, bsum, N);
    k_scan2<<<1, 128, 0, stream>>>(bsum, scanBlocks);
    k_scan3<<<scanBlocks, 256, 0, stream>>>(rowptr, cursor, bsum, N, E);
    k_place<<<edgeBlocks, 256, 0, stream>>>(src, dst, cursor, csr_src, E);

    // ---- node features + attention ----
    k_in_gemm<<<tileBlocks64, 256, 0, stream>>>(x, Win, bin, wp, attw,
                                                A, delta, hwp, ai, aj, N);
    k_neigh_pi<<<nodeBlocks256, 256, 0, stream>>>(rowptr, csr_src, delta, hwp, pi, N);
    k_att<<<nodeBlocks256, 256, 0, stream>>>(rowptr, csr_src, ai, aj, pi,
                                             attw, attb, alpha, N);

    // ---- layers ----
    k_gemm64<<<tileBlocks64, 256, 0, stream>>>(A, W0, b0, Bf, N, 0);
    k_gather<<<nodeBlocksW, 256, 0, stream>>>(rowptr, csr_src, alpha, Bf, C, N);

    k_gemm64<<<tileBlocks64, 256, 0, stream>>>(C, W1, b1, A, N, 1);
    k_gather<<<nodeBlocksW, 256, 0, stream>>>(rowptr, csr_src, alpha, A, Bf, N);

    k_gemm64<<<tileBlocks64, 256, 0, stream>>>(Bf, W2, b2, C, N, 1);
    k_gather<<<nodeBlocksW, 256, 0, stream>>>(rowptr, csr_src, alpha, C, A, N);

    k_out_gemm<<<tileBlocks128, 256, 0, stream>>>(A, Wout, bout, out, N);
}